// Round 17
// baseline (181.048 us; speedup 1.0000x reference)
//
#include <hip/hip_runtime.h>

#define N_NODES 100000
#define N_EDGES 1600000
#define BN_EPS 1e-5f
#define SB 25          // super-buckets of 4096 nodes
#define SCAP 67584     // super capacity (mean 65536 + ~8 sigma), 16.5*4096
#define NBB 800        // SB*32 buckets of 128 nodes
#define CAP 2432       // bucket capacity (mean 2048 + 8.5 sigma)

typedef short short8 __attribute__((ext_vector_type(8)));
typedef float floatx4 __attribute__((ext_vector_type(4)));

__device__ __forceinline__ unsigned short f2bf(float f) {
    unsigned int u = __float_as_uint(f);
    unsigned int r = (u + 0x7fffu + ((u >> 16) & 1u)) >> 16;  // RNE
    return (unsigned short)r;
}
__device__ __forceinline__ float bflo(unsigned int v) { return __uint_as_float(v << 16); }
__device__ __forceinline__ float bfhi(unsigned int v) { return __uint_as_float(v & 0xffff0000u); }

// ---------------- pass A: edges -> 25 super-buckets (+ W conversion in block 0) ----------------
// code = src | (dst_local12 << 17)
__global__ __launch_bounds__(512) void k_binA(const int* __restrict__ ei,
                                              int* __restrict__ scnt,
                                              unsigned int* __restrict__ b1,
                                              const float* __restrict__ Wf,
                                              unsigned short* __restrict__ Wb, int E) {
    __shared__ int hist[32], base[32], gbase[32];
    __shared__ unsigned int stage[4096];
    __shared__ unsigned char stb[4096];
    int tid = threadIdx.x;
    int e0 = blockIdx.x * 4096;
    int cn = min(4096, E - e0);
    if (tid < 32) hist[tid] = 0;
    if (blockIdx.x == 0)
        for (int i = tid; i < 128 * 128; i += 512) Wb[i] = f2bf(Wf[i]);
    __syncthreads();

    unsigned int mycode[8];
    short myslot[8];
    signed char myb[8];
    #pragma unroll
    for (int j = 0; j < 8; j++) {
        int idx = j * 512 + tid;
        if (idx < cn) {
            int src = ei[e0 + idx];
            int dst = ei[E + e0 + idx];
            int s = dst >> 12;
            mycode[j] = (unsigned int)src | ((unsigned int)(dst & 4095) << 17);
            myb[j] = (signed char)s;
            myslot[j] = (short)atomicAdd(&hist[s], 1);
        } else myb[j] = -1;
    }
    __syncthreads();
    if (tid == 0) {
        int run = 0;
        for (int s = 0; s < SB; s++) { base[s] = run; run += hist[s]; }
    }
    __syncthreads();
    #pragma unroll
    for (int j = 0; j < 8; j++) {
        if (myb[j] >= 0) {
            int p = base[myb[j]] + myslot[j];
            stage[p] = mycode[j];
            stb[p] = (unsigned char)myb[j];
        }
    }
    if (tid < SB && hist[tid]) gbase[tid] = tid * SCAP + atomicAdd(&scnt[tid], hist[tid]);
    __syncthreads();
    for (int i = tid; i < cn; i += 512) {
        int s = stb[i];
        b1[gbase[s] + (i - base[s])] = stage[i];
    }
}

// ---------------- pass B: super-bucket -> 32 buckets of 128 nodes (runs = 128) ----------------
// final code = src | (dst_local7 << 17)
__global__ __launch_bounds__(512) void k_binB(const unsigned int* __restrict__ b1,
                                              const int* __restrict__ scnt,
                                              int* __restrict__ bcnt,
                                              unsigned int* __restrict__ b2) {
    __shared__ int hist[32], base[32], gbase[32];
    __shared__ unsigned int stage[4096];
    __shared__ unsigned char stb[4096];
    int tid = threadIdx.x;
    int s = blockIdx.x / 17;
    int c = blockIdx.x % 17;
    int cnt = scnt[s];
    int e0 = s * SCAP + c * 4096;
    int cn = min(4096, cnt - c * 4096);
    if (tid < 32) hist[tid] = 0;
    __syncthreads();

    unsigned int mycode[8];
    short myslot[8];
    signed char myb[8];
    #pragma unroll
    for (int j = 0; j < 8; j++) {
        int idx = j * 512 + tid;
        if (idx < cn) {
            unsigned int code = b1[e0 + idx];
            int sub = (code >> 24) & 31;          // dst_local12 >> 7
            mycode[j] = code & 0x00FFFFFFu;       // src | dst_local7<<17
            myb[j] = (signed char)sub;
            myslot[j] = (short)atomicAdd(&hist[sub], 1);
        } else myb[j] = -1;
    }
    __syncthreads();
    if (tid == 0) {
        int run = 0;
        for (int k = 0; k < 32; k++) { base[k] = run; run += hist[k]; }
    }
    __syncthreads();
    #pragma unroll
    for (int j = 0; j < 8; j++) {
        if (myb[j] >= 0) {
            int p = base[myb[j]] + myslot[j];
            stage[p] = mycode[j];
            stb[p] = (unsigned char)myb[j];
        }
    }
    if (tid < 32 && hist[tid]) {
        int gb = s * 32 + tid;
        gbase[tid] = gb * CAP + atomicAdd(&bcnt[gb], hist[tid]);
    }
    __syncthreads();
    for (int i = tid; i < cn; i += 512) {
        int sub = stb[i];
        b2[gbase[sub] + (i - base[sub])] = stage[i];
    }
}

// ---------------- per-bucket: in-place sort (b2 -> node-grouped src*32), pd = off|deg<<12 ----------------
__global__ __launch_bounds__(256) void k_sortd(unsigned int* __restrict__ b2,
        const int* __restrict__ bcnt, unsigned int* __restrict__ pd, int n) {
    __shared__ unsigned int stage[CAP];
    __shared__ int hist[128], hsc[128];
    int b = blockIdx.x, t = threadIdx.x;
    int nb0 = b * 128;
    int e0 = b * CAP;
    int cnt = bcnt[b];
    if (t < 128) hist[t] = 0;
    __syncthreads();
    for (int i = t; i < cnt; i += 256) {
        unsigned int code = b2[e0 + i];
        stage[i] = code;
        atomicAdd(&hist[code >> 17], 1);
    }
    __syncthreads();
    int v = (t < 128) ? hist[t] : 0;
    if (t < 128) hsc[t] = v;
    __syncthreads();
    for (int o = 1; o < 128; o <<= 1) {
        int x = (t < 128 && t >= o) ? hsc[t - o] : 0;
        __syncthreads();
        if (t < 128) hsc[t] += x;
        __syncthreads();
    }
    int nr = min(128, n - nb0);
    if (t < nr) {
        int start = hsc[t] - v;
        pd[nb0 + t] = (unsigned int)start | ((unsigned int)v << 12);  // local off | deg
        hist[t] = start;                  // reuse as scatter cursor
    }
    __syncthreads();
    for (int i = t; i < cnt; i += 256) {
        unsigned int code = stage[i];
        int pos = atomicAdd(&hist[code >> 17], 1);
        b2[e0 + pos] = (code & 0x1FFFF) << 5;   // pre-scaled uint2 row base (src*32)
    }
}

// ---------------- GEMM g = dinv * (x @ W^T) via bf16 MFMA, g stored as bf16 ----------------
__global__ __launch_bounds__(256) void k_gemm(const float* __restrict__ x,
                                              const unsigned short* __restrict__ Wb,
                                              const unsigned int* __restrict__ pd,
                                              unsigned short* __restrict__ gb, int n) {
    int w = threadIdx.x >> 6;
    int l = threadIdx.x & 63;
    int rowbase = blockIdx.x * 128 + w * 32;
    int r16 = l & 15;
    int kg = l >> 4;

    short8 a[2][4];
    float dv[2][4];
    #pragma unroll
    for (int m = 0; m < 2; m++) {
        int row = rowbase + m * 16 + r16;
        int rca = min(row, n - 1);
        const float* base = x + rca * 128;
        #pragma unroll
        for (int q = 0; q < 4; q++) {
            const float4* xp = (const float4*)(base + q * 32 + kg * 8);
            float4 lo = xp[0], hi = xp[1];
            short8 af;
            af[0] = (short)f2bf(lo.x); af[1] = (short)f2bf(lo.y);
            af[2] = (short)f2bf(lo.z); af[3] = (short)f2bf(lo.w);
            af[4] = (short)f2bf(hi.x); af[5] = (short)f2bf(hi.y);
            af[6] = (short)f2bf(hi.z); af[7] = (short)f2bf(hi.w);
            a[m][q] = af;
        }
        #pragma unroll
        for (int r = 0; r < 4; r++) {
            int rr = min(rowbase + m * 16 + kg * 4 + r, n - 1);
            dv[m][r] = rsqrtf((float)((pd[rr] >> 12) + 1));
        }
    }
    for (int t = 0; t < 8; t++) {
        int col = t * 16 + r16;
        short8 b[4];
        #pragma unroll
        for (int q = 0; q < 4; q++)
            b[q] = *(const short8*)(Wb + col * 128 + q * 32 + kg * 8);

        floatx4 acc[2] = {};
        #pragma unroll
        for (int m = 0; m < 2; m++)
            #pragma unroll
            for (int q = 0; q < 4; q++)
                acc[m] = __builtin_amdgcn_mfma_f32_16x16x32_bf16(a[m][q], b[q], acc[m], 0, 0, 0);

        #pragma unroll
        for (int m = 0; m < 2; m++) {
            #pragma unroll
            for (int r = 0; r < 4; r++) {
                int row = rowbase + m * 16 + kg * 4 + r;
                if (row < n) gb[row * 128 + col] = f2bf(acc[m][r] * dv[m][r]);
            }
        }
    }
}

// ---------------- aggregation: wave per node, whole-row uint2 half-wave pairs ----------------
// out_i(bf16) = dinv_i * (g_i + sum_e g_src); lanes 0-31 / 32-63 handle edge pairs
__global__ __launch_bounds__(256) void k_agg(const uint2* __restrict__ hp2,
        const unsigned int* __restrict__ pd, const unsigned int* __restrict__ csr,
        unsigned int* __restrict__ ob, int n) {
    int w = threadIdx.x >> 6;
    int l = threadIdx.x & 63;
    int i = blockIdx.x * 4 + w;
    if (i >= n) return;
    int half = l >> 5;
    int m = l & 31;                 // uint2 column (4 bf16 cols)
    unsigned int pdi = pd[i];
    int s0 = (i >> 7) * CAP + (int)(pdi & 0xFFF);
    int cnt = (int)(pdi >> 12);
    float di = rsqrtf((float)(cnt + 1));
    float ax0 = 0.f, ay0 = 0.f, ax1 = 0.f, ay1 = 0.f;
    for (int base = 0; base < cnt; base += 64) {
        int rem = min(cnt - base, 64);
        unsigned int my = (l < rem) ? csr[s0 + base + l] : 0u;   // src*32
        int e = 0;
        for (; e + 15 < rem; e += 16) {         // 8 loads/lane (4KB/wave in flight)
            uint2 hv[8];
            #pragma unroll
            for (int j = 0; j < 8; j++) {
                unsigned int s = __shfl(my, e + 2 * j + half);
                hv[j] = hp2[s + m];
            }
            #pragma unroll
            for (int j = 0; j < 8; j++) {
                ax0 += bflo(hv[j].x); ay0 += __uint_as_float(hv[j].x);
                ax1 += bflo(hv[j].y); ay1 += __uint_as_float(hv[j].y);
            }
        }
        for (; e + 1 < rem; e += 2) {
            unsigned int s = __shfl(my, e + half);
            uint2 hv = hp2[s + m];
            ax0 += bflo(hv.x); ay0 += __uint_as_float(hv.x);
            ax1 += bflo(hv.y); ay1 += __uint_as_float(hv.y);
        }
        if (e < rem) {                           // odd leftover: half 0 only
            unsigned int s = __shfl(my, e);
            if (half == 0) {
                uint2 hv = hp2[s + m];
                ax0 += bflo(hv.x); ay0 += __uint_as_float(hv.x);
                ax1 += bflo(hv.y); ay1 += __uint_as_float(hv.y);
            }
        }
    }
    ax0 += __shfl_xor(ax0, 32);
    ay0 += __shfl_xor(ay0, 32);
    ax1 += __shfl_xor(ax1, 32);
    ay1 += __shfl_xor(ay1, 32);
    if (half == 0) {
        uint2 sv = hp2[i * 32 + m];             // self term g_i (exact unpack)
        float v0 = di * (ax0 + bflo(sv.x));
        float v1 = di * (ay0 + bfhi(sv.x));
        float v2 = di * (ax1 + bflo(sv.y));
        float v3 = di * (ay1 + bfhi(sv.y));
        ((uint2*)ob)[i * 32 + m] = make_uint2(
            (unsigned int)f2bf(v0) | ((unsigned int)f2bf(v1) << 16),
            (unsigned int)f2bf(v2) | ((unsigned int)f2bf(v3) << 16));
    }
}

// ---------------- BN stats from bf16 ob ----------------
__global__ void k_stats(const unsigned int* __restrict__ ob, float* __restrict__ sums,
                        float* __restrict__ sumsq, int n) {
    int tid = threadIdx.x;
    int c2 = tid & 63;
    int rh = tid >> 6;  // 0..3
    float s0 = 0, s1 = 0, q0 = 0, q1 = 0;
    for (int r = blockIdx.x * 4 + rh; r < n; r += gridDim.x * 4) {
        unsigned int v = ob[r * 64 + c2];
        float a = bflo(v), b = bfhi(v);
        s0 += a; q0 += a * a;
        s1 += b; q1 += b * b;
    }
    __shared__ float ls[4][128], lq[4][128];
    ls[rh][2 * c2] = s0; ls[rh][2 * c2 + 1] = s1;
    lq[rh][2 * c2] = q0; lq[rh][2 * c2 + 1] = q1;
    __syncthreads();
    if (tid < 128) {
        float s = 0, q = 0;
        #pragma unroll
        for (int j = 0; j < 4; j++) { s += ls[j][tid]; q += lq[j][tid]; }
        atomicAdd(&sums[tid], s);
        atomicAdd(&sumsq[tid], q);
    }
}

// ---------------- BN normalize + ReLU: bf16 ob -> f32 out ----------------
__global__ void k_bn(const unsigned int* __restrict__ ob, float* __restrict__ out,
                     const float* __restrict__ sums, const float* __restrict__ sumsq,
                     const float* __restrict__ gamma, const float* __restrict__ beta, int n) {
    int idx = blockIdx.x * 256 + threadIdx.x;
    if (idx >= n * 64) return;
    int c2 = idx & 63;
    int c0 = 2 * c2, c1 = c0 + 1;
    unsigned int v = ob[idx];
    float invN = 1.0f / (float)n;
    float m0 = sums[c0] * invN, m1 = sums[c1] * invN;
    float sc0 = rsqrtf(sumsq[c0] * invN - m0 * m0 + BN_EPS) * gamma[c0];
    float sc1 = rsqrtf(sumsq[c1] * invN - m1 * m1 + BN_EPS) * gamma[c1];
    float o0 = fmaxf((bflo(v) - m0) * sc0 + beta[c0], 0.0f);
    float o1 = fmaxf((bfhi(v) - m1) * sc1 + beta[c1], 0.0f);
    ((float2*)out)[idx] = make_float2(o0, o1);
}

extern "C" void kernel_launch(void* const* d_in, const int* in_sizes, int n_in,
                              void* d_out, int out_size, void* d_ws, size_t ws_size,
                              hipStream_t stream) {
    const float* x     = (const float*)d_in[0];
    const int*   ei    = (const int*)d_in[1];     // [2][E]
    const float* W     = (const float*)d_in[2];
    // d_in[3] = b : cancels exactly under training-mode BatchNorm -> unused
    const float* gamma = (const float*)d_in[4];
    const float* beta  = (const float*)d_in[5];
    float* out = (float*)d_out;

    const int n = N_NODES, E = N_EDGES;

    // workspace layout (~59.4 MB; b1 aliases ob, both dead/live at disjoint times)
    unsigned short* gbuf = (unsigned short*)d_ws;          // 12.8M bf16 (25.6 MB)
    unsigned int* pd = (unsigned int*)(gbuf + 12800000);   // 100k u32 (off|deg<<12)
    float* sums   = (float*)(pd + 100000);                 // 128  (zero region start)
    float* sumsq  = sums + 128;                            // 128
    int*   bcnt   = (int*)(sumsq + 128);                   // NBB
    int*   scnt   = bcnt + NBB;                            // SB   (zero region end)
    unsigned short* Wb = (unsigned short*)(scnt + SB);     // 16384 bf16
    unsigned int* b2 = (unsigned int*)(Wb + 16384);        // NBB*CAP u32 (7.8 MB) -> src-lists
    unsigned int* ob = b2 + NBB * CAP;                     // 6.4M u32 (25.6 MB)
    unsigned int* b1 = ob;                                 // alias: b1 (6.8 MB) dead before ob written

    hipMemsetAsync(sums, 0, (256 + NBB + SB) * sizeof(int), stream);

    k_binA<<<(E + 4095) / 4096, 512, 0, stream>>>(ei, scnt, b1, W, Wb, E);
    k_binB<<<SB * 17, 512, 0, stream>>>(b1, scnt, bcnt, b2);
    k_sortd<<<NBB, 256, 0, stream>>>(b2, bcnt, pd, n);

    k_gemm<<<(n + 127) / 128, 256, 0, stream>>>(x, Wb, pd, gbuf, n);

    k_agg<<<(n + 3) / 4, 256, 0, stream>>>((const uint2*)gbuf, pd,
                                           (const unsigned int*)b2, ob, n);

    k_stats<<<512, 256, 0, stream>>>(ob, sums, sumsq, n);
    k_bn<<<(n * 64 + 255) / 256, 256, 0, stream>>>(ob, out, sums, sumsq, gamma, beta, n);
}